// Round 7
// baseline (704.943 us; speedup 1.0000x reference)
//
#include <hip/hip_runtime.h>
#include <hip/hip_bf16.h>
#include <math.h>

// Problem constants (match reference)
#define N_NODES   50000
#define N_EDGESC  800000
#define IN_DIM    768
#define HID       256
#define OUT_DIM   9
#define EDGE_FEAT 100
#define P_DROP    0.4f
#define INV_KEEP  (1.0f/0.6f)

typedef __attribute__((ext_vector_type(8))) short bf16x8;
typedef __attribute__((ext_vector_type(4))) float f32x4;

__device__ __forceinline__ ushort f2bf(float f) {
    uint u = __float_as_uint(f);
    uint r = (u + 0x7fffu + ((u >> 16) & 1u)) >> 16;   // RNE
    return (ushort)r;
}
__device__ __forceinline__ float bf2f(ushort h) {
    return __uint_as_float(((uint)h) << 16);
}
// packed f32x2 -> bf16x2 (v_cvt_pk_bf16_f32)
__device__ __forceinline__ uint pack_bf2(float a, float b) {
    __hip_bfloat162 h2 = __float22bfloat162_rn(make_float2(a, b));
    uint r; __builtin_memcpy(&r, &h2, 4); return r;
}

// LDS XOR swizzle: byte ^ ((row&7)<<4); bijective within 128B rows; r6 measured
// SQ_LDS_BANK_CONFLICT == 0 with this scheme.
__device__ __forceinline__ int swz2(int row, int byte) { return byte ^ ((row & 7) << 4); }

// ---------------------------------------------------------------------------
// K0: xprep — x (f32) -> xb (bf16), one pass. Removes per-nb-block re-read of
// fp32 x (614MB logical -> 307MB bf16) and all conversion VALU from gemm1.
// ---------------------------------------------------------------------------
__global__ __launch_bounds__(256) void xprep(const float* __restrict__ x, ushort* __restrict__ xb) {
    const int total = (N_NODES*IN_DIM)/8;     // 4.8M chunks of 8
    const int stride = 2048*256;
    for (int i = blockIdx.x*256 + threadIdx.x; i < total; i += stride) {
        const float4* p = (const float4*)(x + (size_t)i*8);
        const float4 v0 = p[0], v1 = p[1];
        uint o[4];
        o[0] = pack_bf2(v0.x, v0.y); o[1] = pack_bf2(v0.z, v0.w);
        o[2] = pack_bf2(v1.x, v1.y); o[3] = pack_bf2(v1.z, v1.w);
        *(uint4*)(xb + (size_t)i*8) = *(uint4*)o;
    }
}

// ---------------------------------------------------------------------------
// K1: gate tables. tbl: [0,50) tdot1 | [50,178) ddot1 | [178,228) tdot2 | [228,356) ddot2
// ---------------------------------------------------------------------------
__global__ void gate_tables(const float* __restrict__ te1, const float* __restrict__ de1,
                            const float* __restrict__ g1w,
                            const float* __restrict__ te2, const float* __restrict__ de2,
                            const float* __restrict__ g2w,
                            float* __restrict__ tbl) {
    int t = threadIdx.x;
    const float* vec; const float* w;
    if (t < 50)       { vec = te1 + t*EDGE_FEAT;         w = g1w; }
    else if (t < 178) { vec = de1 + (t-50)*EDGE_FEAT;    w = g1w + EDGE_FEAT; }
    else if (t < 228) { vec = te2 + (t-178)*EDGE_FEAT;   w = g2w; }
    else if (t < 356) { vec = de2 + (t-228)*EDGE_FEAT;   w = g2w + EDGE_FEAT; }
    else return;
    float s = 0.f;
    for (int i = 0; i < EDGE_FEAT; ++i) s += vec[i]*w[i];
    tbl[t] = s;
}

// ---------------------------------------------------------------------------
// B' prep for gemm1: BT[n][k] bf16, n in [0,512) = [Wmsg | Wroot]
// ---------------------------------------------------------------------------
__global__ __launch_bounds__(256) void bt_prep(const float* __restrict__ Wm, const float* __restrict__ Wr,
                                               ushort* __restrict__ BTh) {
    int tid = blockIdx.x*256 + threadIdx.x;
    if (tid >= 512*IN_DIM) return;
    int n = tid / IN_DIM, k = tid % IN_DIM;
    float w = (n < HID) ? Wm[(size_t)k*HID + n] : Wr[(size_t)k*HID + (n - HID)];
    BTh[tid] = f2bf(w);
}

// ---------------------------------------------------------------------------
// W2 pack: WPT[32][256] bf16 = B^T; cols 0..8 = W2_msg, 16..24 = W2_root.
// ---------------------------------------------------------------------------
__global__ __launch_bounds__(256) void w2_pack(const float* __restrict__ Wm, const float* __restrict__ Wr,
                                               ushort* __restrict__ WPT) {
    int i = blockIdx.x*256 + threadIdx.x;
    if (i >= 32*256) return;
    int col = i >> 8, k = i & 255;
    float v = 0.f;
    if (col < 9)                    v = Wm[(size_t)k*OUT_DIM + col];
    else if (col >= 16 && col < 25) v = Wr[(size_t)k*OUT_DIM + (col - 16)];
    WPT[i] = f2bf(v);
}

// ---------------------------------------------------------------------------
// CSR build: histogram -> 3-pass scan -> bucket fill.
// ---------------------------------------------------------------------------
__global__ __launch_bounds__(256) void zero_deg(int* __restrict__ deg) {
    int i = blockIdx.x*256 + threadIdx.x;
    if (i < N_NODES) deg[i] = 0;
}

__global__ __launch_bounds__(256) void hist(const int* __restrict__ dst, int* __restrict__ deg) {
    int e = blockIdx.x*256 + threadIdx.x;
    if (e < N_EDGESC) atomicAdd(&deg[dst[e]], 1);
}

__global__ __launch_bounds__(256) void scan_p1(const int* __restrict__ deg, int* __restrict__ bsum) {
    __shared__ int sd[256];
    int i = blockIdx.x*256 + threadIdx.x;
    sd[threadIdx.x] = (i < N_NODES) ? deg[i] : 0;
    __syncthreads();
    for (int off = 128; off; off >>= 1) {
        if (threadIdx.x < off) sd[threadIdx.x] += sd[threadIdx.x + off];
        __syncthreads();
    }
    if (!threadIdx.x) bsum[blockIdx.x] = sd[0];
}

__global__ __launch_bounds__(256) void scan_p2(const int* __restrict__ bsum, int* __restrict__ boff) {
    __shared__ int ps[256];
    const int t = threadIdx.x;
    const int NB = 196;
    int v = (t < NB) ? bsum[t] : 0;
    ps[t] = v;
    __syncthreads();
    for (int off = 1; off < 256; off <<= 1) {
        int u = (t >= off) ? ps[t-off] : 0;
        __syncthreads();
        ps[t] += u;
        __syncthreads();
    }
    if (t < NB) boff[t] = ps[t] - v;
}

__global__ __launch_bounds__(256) void scan_p3(const int* __restrict__ deg, const int* __restrict__ boff,
                                               int* __restrict__ rowptr, int* __restrict__ cursor) {
    __shared__ int ps[256];
    const int t = threadIdx.x;
    const int i = blockIdx.x*256 + t;
    int v = (i < N_NODES) ? deg[i] : 0;
    ps[t] = v;
    __syncthreads();
    for (int off = 1; off < 256; off <<= 1) {
        int u = (t >= off) ? ps[t-off] : 0;
        __syncthreads();
        ps[t] += u;
        __syncthreads();
    }
    if (i < N_NODES) {
        int ex = boff[blockIdx.x] + ps[t] - v;
        rowptr[i] = ex;
        cursor[i] = ex;
        if (i == N_NODES-1) rowptr[N_NODES] = ex + v;
    }
}

__global__ __launch_bounds__(256) void fill_csr(const int* __restrict__ src, const int* __restrict__ dst,
                                                const int* __restrict__ etype, const int* __restrict__ edist,
                                                const float* __restrict__ tbl,
                                                const float* __restrict__ g1b, const float* __restrict__ g2b,
                                                int* __restrict__ cursor,
                                                int* __restrict__ esrc, float* __restrict__ a1, float* __restrict__ a2) {
    int e = blockIdx.x*256 + threadIdx.x;
    if (e >= N_EDGESC) return;
    const int tt = etype[e], dd = edist[e];
    const float z1 = tbl[tt]       + tbl[50 + dd]  + g1b[0];
    const float z2 = tbl[178 + tt] + tbl[228 + dd] + g2b[0];
    const int pos = atomicAdd(&cursor[dst[e]], 1);
    esrc[pos] = src[e];
    a1[pos] = 1.f / (1.f + expf(-z1));
    a2[pos] = 1.f / (1.f + expf(-z2));
}

// ---------------------------------------------------------------------------
// K2: bf16 MFMA GEMM1: C[50000 x 512] = xb @ [W1_msg | W1_root]
// A pre-converted (xprep) -> staging is 4+4 uint4 regs/thread, no spills.
// BK=64, 32KB swizzled LDS. msg half -> xtb (bf16), root half -> h (f32, +b1).
// ---------------------------------------------------------------------------
#define G1_BK 64

__global__ __launch_bounds__(256) void gemm1_mfma(const ushort* __restrict__ xb,
                                                  const ushort* __restrict__ BTh,
                                                  const float* __restrict__ b1,
                                                  ushort* __restrict__ xtb,
                                                  float* __restrict__ h) {
    __shared__ __align__(16) ushort Ah[128*G1_BK];   // 16KB, 128B rows, swizzled
    __shared__ __align__(16) ushort Bh[128*G1_BK];   // 16KB

    const int t    = threadIdx.x;
    const int wave = t >> 6, lane = t & 63;
    const int wm   = wave >> 1, wn = wave & 1;
    const int nb   = blockIdx.x;         // 0..3 column block (x-fastest: A sharers adjacent)
    const int m0   = blockIdx.y * 128;
    const int n0   = nb * 128;

    // staging maps: 2 threads/row, 32 bf16 (64B) each
    const int sr = t >> 1;
    const int sk = (t & 1) * 32;
    const int arow   = m0 + sr;
    const bool avalid = arow < N_NODES;
    const ushort* ap = xb  + (size_t)(avalid ? arow : 0) * IN_DIM + sk;
    const ushort* bp = BTh + (size_t)(n0 + sr) * IN_DIM + sk;

    const int fr = lane & 15;
    const int kg = lane >> 4;

    f32x4 acc[4][4];
    #pragma unroll
    for (int i=0;i<4;i++)
        #pragma unroll
        for (int j=0;j<4;j++) acc[i][j] = (f32x4){0.f,0.f,0.f,0.f};

    uint4 av[4], bv[4];
    auto stage_load = [&](int kb) {
        if (avalid) {
            const uint4* pa = (const uint4*)(ap + kb);
            #pragma unroll
            for (int i=0;i<4;i++) av[i] = pa[i];
        } else {
            #pragma unroll
            for (int i=0;i<4;i++) av[i] = make_uint4(0u,0u,0u,0u);
        }
        const uint4* pb = (const uint4*)(bp + kb);
        #pragma unroll
        for (int i=0;i<4;i++) bv[i] = pb[i];
    };

    char* const cA = (char*)Ah;
    char* const cB = (char*)Bh;
    const int wb = sr*128 + sk*2;        // base byte of this thread's 64B slot

    stage_load(0);
    for (int kb = 0; kb < IN_DIM; kb += G1_BK) {
        __syncthreads();   // previous iteration's ds_reads complete
        #pragma unroll
        for (int i=0;i<4;i++) {
            *(uint4*)(cA + swz2(sr, wb + i*16)) = av[i];
            *(uint4*)(cB + swz2(sr, wb + i*16)) = bv[i];
        }
        __syncthreads();
        if (kb + G1_BK < IN_DIM) stage_load(kb + G1_BK);   // overlap with MFMAs

        #pragma unroll
        for (int kk=0; kk<2; kk++) {
            bf16x8 af[4], bfv[4];
            #pragma unroll
            for (int i=0;i<4;i++) {
                const int r = wm*64 + i*16 + fr;
                af[i] = *(const bf16x8*)(cA + swz2(r, r*128 + kk*64 + kg*16));
            }
            #pragma unroll
            for (int j=0;j<4;j++) {
                const int c = wn*64 + j*16 + fr;
                bfv[j] = *(const bf16x8*)(cB + swz2(c, c*128 + kk*64 + kg*16));
            }
            #pragma unroll
            for (int i=0;i<4;i++)
                #pragma unroll
                for (int j=0;j<4;j++)
                    acc[i][j] = __builtin_amdgcn_mfma_f32_16x16x32_bf16(af[i], bfv[j], acc[i][j], 0, 0, 0);
        }
    }

    // epilogue: C/D map col=lane&15, row=(lane>>4)*4+reg  [m89/m91]
    const bool is_root = (nb >= 2);
    if (is_root) {
        const int cb = n0 - 256;
        #pragma unroll
        for (int j=0;j<4;j++) {
            const int col  = cb + wn*64 + j*16 + fr;
            const float bias = b1[col];
            #pragma unroll
            for (int i=0;i<4;i++) {
                const int rbase = m0 + wm*64 + i*16 + kg*4;
                #pragma unroll
                for (int r=0;r<4;r++) {
                    const int row = rbase + r;
                    if (row < N_NODES) h[(size_t)row*HID + col] = acc[i][j][r] + bias;
                }
            }
        }
    } else {
        #pragma unroll
        for (int j=0;j<4;j++) {
            const int col = n0 + wn*64 + j*16 + fr;
            #pragma unroll
            for (int i=0;i<4;i++) {
                const int rbase = m0 + wm*64 + i*16 + kg*4;
                #pragma unroll
                for (int r=0;r<4;r++) {
                    const int row = rbase + r;
                    if (row < N_NODES) xtb[(size_t)row*HID + col] = f2bf(acc[i][j][r]);
                }
            }
        }
    }
}

// ---------------------------------------------------------------------------
// K3: gather1 — one wave per dst node, EIGHT edges in flight:
// lane group g=lane>>3 owns edge j+g; 8 lanes/edge cover the 512B bf16 row
// (4x uint4 each). Fold via shfl_xor 8/16/32. Epilogue fuses root add +
// dropout + relu, writes activated h as bf16 (hb).
// ---------------------------------------------------------------------------
__global__ __launch_bounds__(256) void gather1(const int* __restrict__ rowptr,
                                               const int* __restrict__ esrc, const float* __restrict__ a1,
                                               const ushort* __restrict__ xtb,
                                               const float* __restrict__ h,
                                               const float* __restrict__ drop1,
                                               ushort* __restrict__ hb) {
    const int node = blockIdx.x*4 + (threadIdx.x >> 6);
    const int lane = threadIdx.x & 63;
    if (node >= N_NODES) return;
    const int g = lane >> 3, li = lane & 7;
    const int colbase = li*32;           // 32 bf16 = 64B per lane
    const int beg = rowptr[node], end = rowptr[node+1];

    float acc[32];
    #pragma unroll
    for (int q=0;q<32;q++) acc[q] = 0.f;

    for (int j = beg; j < end; j += 8) {
        const int jj = j + g;
        int s = 0; float a = 0.f;
        if (jj < end) { s = esrc[jj]; a = a1[jj]; }
        const uint4* sp = (const uint4*)(xtb + (size_t)s*HID + colbase);
        uint4 v[4];
        #pragma unroll
        for (int i=0;i<4;i++) v[i] = sp[i];
        const uint* vw = (const uint*)v;
        #pragma unroll
        for (int q=0;q<16;q++) {
            acc[2*q]   = fmaf(a, bf2f((ushort)(vw[q] & 0xffffu)), acc[2*q]);
            acc[2*q+1] = fmaf(a, bf2f((ushort)(vw[q] >> 16)),     acc[2*q+1]);
        }
    }
    #pragma unroll
    for (int q=0;q<32;q++) {
        acc[q] += __shfl_xor(acc[q], 8, 64);
        acc[q] += __shfl_xor(acc[q], 16, 64);
        acc[q] += __shfl_xor(acc[q], 32, 64);
    }

    if (g == 0) {
        const float* hp = h + (size_t)node*HID + colbase;
        const float* dp = drop1 + (size_t)node*HID + colbase;
        uint o[16];
        #pragma unroll
        for (int q=0;q<16;q++) {
            const float2 hv = ((const float2*)hp)[q];
            const float2 dv = ((const float2*)dp)[q];
            float m0 = (dv.x >= P_DROP) ? INV_KEEP : 0.f;
            float m1 = (dv.y >= P_DROP) ? INV_KEEP : 0.f;
            float f0 = fmaxf((hv.x + acc[2*q])   * m0, 0.f);
            float f1 = fmaxf((hv.y + acc[2*q+1]) * m1, 0.f);
            o[q] = pack_bf2(f0, f1);
        }
        ushort* op = hb + (size_t)node*HID + colbase;
        #pragma unroll
        for (int i=0;i<4;i++) *(uint4*)(op + i*8) = *(uint4*)&o[4*i];
    }
}

// ---------------------------------------------------------------------------
// K4: gemm2 MFMA: [128 rows x 32 cols] = hb[128 x 256] @ WPT^T.
// acc col frag 0 -> ht2 (W2_msg), frag 1 -> root2 (W2_root + b2).
// ---------------------------------------------------------------------------
__global__ __launch_bounds__(256) void gemm2_mfma(const ushort* __restrict__ hb,
                                                  const ushort* __restrict__ WPT,
                                                  const float* __restrict__ b2,
                                                  float* __restrict__ ht2, float* __restrict__ root2) {
    __shared__ __align__(16) ushort As[128*256];   // 64KB, 512B rows, swizzled
    __shared__ __align__(16) ushort Bs[32*256];    // 16KB

    const int t = threadIdx.x;
    const int m0 = blockIdx.x * 128;
    char* const cAs = (char*)As;
    char* const cBs = (char*)Bs;

    #pragma unroll
    for (int i = 0; i < 4; ++i) {                  // stage B: 8192 elems / 8 per uint4
        const int idx = (i*256 + t) * 8;
        const int row = idx >> 8, col = idx & 255;
        const uint4 v = *(const uint4*)(WPT + row*256 + col);
        *(uint4*)(cBs + swz2(row, row*512 + col*2)) = v;
    }
    #pragma unroll
    for (int i = 0; i < 16; ++i) {                 // stage A: 32768 elems / 8 per uint4
        const int idx = (i*256 + t) * 8;
        const int row = idx >> 8, col = idx & 255;
        const int gr = m0 + row;
        uint4 v = make_uint4(0u,0u,0u,0u);
        if (gr < N_NODES) v = *(const uint4*)(hb + (size_t)gr*HID + col);
        *(uint4*)(cAs + swz2(row, row*512 + col*2)) = v;
    }
    __syncthreads();

    const int w = t >> 6, lane = t & 63;
    const int fr = lane & 15, kg = lane >> 4;

    f32x4 acc[2][2];
    #pragma unroll
    for (int i=0;i<2;i++)
        #pragma unroll
        for (int j=0;j<2;j++) acc[i][j] = (f32x4){0.f,0.f,0.f,0.f};

    #pragma unroll
    for (int ks = 0; ks < 8; ++ks) {
        bf16x8 af[2], bfv[2];
        #pragma unroll
        for (int i=0;i<2;i++) {
            const int r = w*32 + i*16 + fr;
            af[i] = *(const bf16x8*)(cAs + swz2(r, r*512 + ks*64 + kg*16));
        }
        #pragma unroll
        for (int j=0;j<2;j++) {
            const int c = j*16 + fr;
            bfv[j] = *(const bf16x8*)(cBs + swz2(c, c*512 + ks*64 + kg*16));
        }
        #pragma unroll
        for (int i=0;i<2;i++)
            #pragma unroll
            for (int j=0;j<2;j++)
                acc[i][j] = __builtin_amdgcn_mfma_f32_16x16x32_bf16(af[i], bfv[j], acc[i][j], 0, 0, 0);
    }

    if (fr < OUT_DIM) {
        const float bias = b2[fr];
        #pragma unroll
        for (int i=0;i<2;i++) {
            const int rbase = m0 + w*32 + i*16 + kg*4;
            #pragma unroll
            for (int r=0;r<4;r++) {
                const int row = rbase + r;
                if (row < N_NODES) {
                    ht2  [(size_t)row*OUT_DIM + fr] = acc[i][0][r];
                    root2[(size_t)row*OUT_DIM + fr] = acc[i][1][r] + bias;
                }
            }
        }
    }
}

// ---------------------------------------------------------------------------
// K5: gather2 — one thread per node, 9-float accumulator; fused relu-dropout.
// ---------------------------------------------------------------------------
__global__ __launch_bounds__(256) void gather2(const int* __restrict__ rowptr,
                                               const int* __restrict__ esrc, const float* __restrict__ a2,
                                               const float* __restrict__ ht2,
                                               const float* __restrict__ root2,
                                               const float* __restrict__ drop2,
                                               float* __restrict__ outp) {
    const int n = blockIdx.x*256 + threadIdx.x;
    if (n >= N_NODES) return;
    float acc[OUT_DIM];
    #pragma unroll
    for (int k=0;k<OUT_DIM;k++) acc[k] = root2[(size_t)n*OUT_DIM + k];
    const int beg = rowptr[n], end = rowptr[n+1];
    for (int j = beg; j < end; ++j) {
        const int s = esrc[j];
        const float a = a2[j];
        const float* sp = ht2 + (size_t)s*OUT_DIM;
        #pragma unroll
        for (int k=0;k<OUT_DIM;k++) acc[k] = fmaf(a, sp[k], acc[k]);
    }
    #pragma unroll
    for (int k=0;k<OUT_DIM;k++) {
        const float m = (drop2[(size_t)n*OUT_DIM + k] >= P_DROP) ? INV_KEEP : 0.f;
        const float v = acc[k]*m;
        outp[(size_t)n*OUT_DIM + k] = v > 0.f ? v : 0.f;
    }
}

// ---------------------------------------------------------------------------
extern "C" void kernel_launch(void* const* d_in, const int* in_sizes, int n_in,
                              void* d_out, int out_size, void* d_ws, size_t ws_size,
                              hipStream_t stream) {
    const float* x      = (const float*)d_in[0];
    const int*   eidx   = (const int*)d_in[1];
    const int*   etype  = (const int*)d_in[2];
    const int*   edist  = (const int*)d_in[3];
    const float* drop1  = (const float*)d_in[4];
    const float* drop2  = (const float*)d_in[5];
    const float* W1m    = (const float*)d_in[6];
    const float* W1r    = (const float*)d_in[7];
    const float* b1     = (const float*)d_in[8];
    const float* te1    = (const float*)d_in[9];
    const float* de1    = (const float*)d_in[10];
    const float* g1w    = (const float*)d_in[11];
    const float* g1b    = (const float*)d_in[12];
    const float* W2m    = (const float*)d_in[13];
    const float* W2r    = (const float*)d_in[14];
    const float* b2     = (const float*)d_in[15];
    const float* te2    = (const float*)d_in[16];
    const float* de2    = (const float*)d_in[17];
    const float* g2w    = (const float*)d_in[18];
    const float* g2b    = (const float*)d_in[19];
    float* out = (float*)d_out;

    const int* src = eidx;
    const int* dst = eidx + N_EDGESC;

    // workspace layout (~168MB); hb aliases xb (xb dead after gemm1)
    float* ws    = (float*)d_ws;
    float* h     = ws;                                   // 12,800,000 f
    float* ht2   = h     + (size_t)N_NODES*HID;          // 450,000 f
    float* root2 = ht2   + (size_t)N_NODES*OUT_DIM;      // 450,000 f
    float* tbl   = root2 + (size_t)N_NODES*OUT_DIM;      // 384 f
    float* a1    = tbl   + 384;                          // 800,000 f
    float* a2    = a1    + N_EDGESC;                     // 800,000 f
    int*   esrc  = (int*)(a2 + N_EDGESC);                // 800,000 i
    int*   deg   = esrc  + N_EDGESC;                     // 50,000 i
    int*   rowptr= deg   + N_NODES;                      // -> pad 50,004
    int*   cursor= rowptr+ 50004;                        // -> pad 50,004
    int*   bsum  = cursor+ 50004;                        // pad 256
    int*   boff  = bsum  + 256;                          // pad 256
    ushort* xtb  = (ushort*)(boff + 256);                // 12,800,000 u16
    ushort* xb   = xtb + (size_t)N_NODES*HID;            // 38,400,000 u16
    ushort* hb   = xb;                                   // alias: 12,800,000 u16
    ushort* BTh  = xb  + (size_t)N_NODES*IN_DIM;         // 393,216 u16
    ushort* WPT  = BTh + (size_t)512*IN_DIM;             // 8,192 u16

    xprep<<<2048, 256, 0, stream>>>(x, xb);
    gate_tables<<<1, 512, 0, stream>>>(te1, de1, g1w, te2, de2, g2w, tbl);
    bt_prep<<<(512*IN_DIM+255)/256, 256, 0, stream>>>(W1m, W1r, BTh);
    w2_pack<<<32, 256, 0, stream>>>(W2m, W2r, WPT);
    zero_deg<<<(N_NODES+255)/256, 256, 0, stream>>>(deg);
    hist<<<(N_EDGESC+255)/256, 256, 0, stream>>>(dst, deg);
    scan_p1<<<196, 256, 0, stream>>>(deg, bsum);
    scan_p2<<<1, 256, 0, stream>>>(bsum, boff);
    scan_p3<<<196, 256, 0, stream>>>(deg, boff, rowptr, cursor);
    fill_csr<<<(N_EDGESC+255)/256, 256, 0, stream>>>(src, dst, etype, edist, tbl, g1b, g2b,
                                                     cursor, esrc, a1, a2);
    gemm1_mfma<<<dim3(4, (N_NODES+127)/128), 256, 0, stream>>>(xb, BTh, b1, xtb, h);
    gather1<<<(N_NODES+3)/4, 256, 0, stream>>>(rowptr, esrc, a1, xtb, h, drop1, hb);
    gemm2_mfma<<<(N_NODES+127)/128, 256, 0, stream>>>(hb, WPT, b2, ht2, root2);
    gather2<<<(N_NODES+255)/256, 256, 0, stream>>>(rowptr, esrc, a2, ht2, root2, drop2, out);
}

// Round 8
// 637.406 us; speedup vs baseline: 1.1060x; 1.1060x over previous
//
#include <hip/hip_runtime.h>
#include <hip/hip_bf16.h>
#include <math.h>

// Problem constants (match reference)
#define N_NODES   50000
#define N_EDGESC  800000
#define IN_DIM    768
#define HID       256
#define OUT_DIM   9
#define EDGE_FEAT 100
#define P_DROP    0.4f
#define INV_KEEP  (1.0f/0.6f)

typedef __attribute__((ext_vector_type(8))) short bf16x8;
typedef __attribute__((ext_vector_type(4))) float f32x4;

__device__ __forceinline__ ushort f2bf(float f) {
    uint u = __float_as_uint(f);
    uint r = (u + 0x7fffu + ((u >> 16) & 1u)) >> 16;   // RNE
    return (ushort)r;
}
__device__ __forceinline__ float bf2f(ushort h) {
    return __uint_as_float(((uint)h) << 16);
}
// packed f32x2 -> bf16x2 (v_cvt_pk_bf16_f32)
__device__ __forceinline__ uint pack_bf2(float a, float b) {
    __hip_bfloat162 h2 = __float22bfloat162_rn(make_float2(a, b));
    uint r; __builtin_memcpy(&r, &h2, 4); return r;
}

// LDS XOR swizzle: byte ^ ((row&7)<<4); bijective within 128B rows; measured
// SQ_LDS_BANK_CONFLICT == 0 with this scheme (r5-r7).
__device__ __forceinline__ int swz2(int row, int byte) { return byte ^ ((row & 7) << 4); }

// ---------------------------------------------------------------------------
// K0: xprep — x (f32) -> xb (bf16), one pass.
// ---------------------------------------------------------------------------
__global__ __launch_bounds__(256) void xprep(const float* __restrict__ x, ushort* __restrict__ xb) {
    const int total = (N_NODES*IN_DIM)/8;     // 4.8M chunks of 8
    const int stride = 2048*256;
    for (int i = blockIdx.x*256 + threadIdx.x; i < total; i += stride) {
        const float4* p = (const float4*)(x + (size_t)i*8);
        const float4 v0 = p[0], v1 = p[1];
        uint o0 = pack_bf2(v0.x, v0.y), o1 = pack_bf2(v0.z, v0.w);
        uint o2 = pack_bf2(v1.x, v1.y), o3 = pack_bf2(v1.z, v1.w);
        uint4 o = make_uint4(o0, o1, o2, o3);
        *(uint4*)(xb + (size_t)i*8) = o;
    }
}

// ---------------------------------------------------------------------------
// K1: gate tables. tbl: [0,50) tdot1 | [50,178) ddot1 | [178,228) tdot2 | [228,356) ddot2
// ---------------------------------------------------------------------------
__global__ void gate_tables(const float* __restrict__ te1, const float* __restrict__ de1,
                            const float* __restrict__ g1w,
                            const float* __restrict__ te2, const float* __restrict__ de2,
                            const float* __restrict__ g2w,
                            float* __restrict__ tbl) {
    int t = threadIdx.x;
    const float* vec; const float* w;
    if (t < 50)       { vec = te1 + t*EDGE_FEAT;         w = g1w; }
    else if (t < 178) { vec = de1 + (t-50)*EDGE_FEAT;    w = g1w + EDGE_FEAT; }
    else if (t < 228) { vec = te2 + (t-178)*EDGE_FEAT;   w = g2w; }
    else if (t < 356) { vec = de2 + (t-228)*EDGE_FEAT;   w = g2w + EDGE_FEAT; }
    else return;
    float s = 0.f;
    for (int i = 0; i < EDGE_FEAT; ++i) s += vec[i]*w[i];
    tbl[t] = s;
}

// ---------------------------------------------------------------------------
// B' prep for gemm1: BT[n][k] bf16, n in [0,512) = [Wmsg | Wroot]
// ---------------------------------------------------------------------------
__global__ __launch_bounds__(256) void bt_prep(const float* __restrict__ Wm, const float* __restrict__ Wr,
                                               ushort* __restrict__ BTh) {
    int tid = blockIdx.x*256 + threadIdx.x;
    if (tid >= 512*IN_DIM) return;
    int n = tid / IN_DIM, k = tid % IN_DIM;
    float w = (n < HID) ? Wm[(size_t)k*HID + n] : Wr[(size_t)k*HID + (n - HID)];
    BTh[tid] = f2bf(w);
}

// ---------------------------------------------------------------------------
// W2 pack: WPT[32][256] bf16 = B^T; cols 0..8 = W2_msg, 16..24 = W2_root.
// ---------------------------------------------------------------------------
__global__ __launch_bounds__(256) void w2_pack(const float* __restrict__ Wm, const float* __restrict__ Wr,
                                               ushort* __restrict__ WPT) {
    int i = blockIdx.x*256 + threadIdx.x;
    if (i >= 32*256) return;
    int col = i >> 8, k = i & 255;
    float v = 0.f;
    if (col < 9)                    v = Wm[(size_t)k*OUT_DIM + col];
    else if (col >= 16 && col < 25) v = Wr[(size_t)k*OUT_DIM + (col - 16)];
    WPT[i] = f2bf(v);
}

// ---------------------------------------------------------------------------
// CSR build: histogram -> 3-pass scan -> bucket fill.
// ---------------------------------------------------------------------------
__global__ __launch_bounds__(256) void zero_deg(int* __restrict__ deg) {
    int i = blockIdx.x*256 + threadIdx.x;
    if (i < N_NODES) deg[i] = 0;
}

__global__ __launch_bounds__(256) void hist(const int* __restrict__ dst, int* __restrict__ deg) {
    int e = blockIdx.x*256 + threadIdx.x;
    if (e < N_EDGESC) atomicAdd(&deg[dst[e]], 1);
}

__global__ __launch_bounds__(256) void scan_p1(const int* __restrict__ deg, int* __restrict__ bsum) {
    __shared__ int sd[256];
    int i = blockIdx.x*256 + threadIdx.x;
    sd[threadIdx.x] = (i < N_NODES) ? deg[i] : 0;
    __syncthreads();
    for (int off = 128; off; off >>= 1) {
        if (threadIdx.x < off) sd[threadIdx.x] += sd[threadIdx.x + off];
        __syncthreads();
    }
    if (!threadIdx.x) bsum[blockIdx.x] = sd[0];
}

__global__ __launch_bounds__(256) void scan_p2(const int* __restrict__ bsum, int* __restrict__ boff) {
    __shared__ int ps[256];
    const int t = threadIdx.x;
    const int NB = 196;
    int v = (t < NB) ? bsum[t] : 0;
    ps[t] = v;
    __syncthreads();
    for (int off = 1; off < 256; off <<= 1) {
        int u = (t >= off) ? ps[t-off] : 0;
        __syncthreads();
        ps[t] += u;
        __syncthreads();
    }
    if (t < NB) boff[t] = ps[t] - v;
}

__global__ __launch_bounds__(256) void scan_p3(const int* __restrict__ deg, const int* __restrict__ boff,
                                               int* __restrict__ rowptr, int* __restrict__ cursor) {
    __shared__ int ps[256];
    const int t = threadIdx.x;
    const int i = blockIdx.x*256 + t;
    int v = (i < N_NODES) ? deg[i] : 0;
    ps[t] = v;
    __syncthreads();
    for (int off = 1; off < 256; off <<= 1) {
        int u = (t >= off) ? ps[t-off] : 0;
        __syncthreads();
        ps[t] += u;
        __syncthreads();
    }
    if (i < N_NODES) {
        int ex = boff[blockIdx.x] + ps[t] - v;
        rowptr[i] = ex;
        cursor[i] = ex;
        if (i == N_NODES-1) rowptr[N_NODES] = ex + v;
    }
}

__global__ __launch_bounds__(256) void fill_csr(const int* __restrict__ src, const int* __restrict__ dst,
                                                const int* __restrict__ etype, const int* __restrict__ edist,
                                                const float* __restrict__ tbl,
                                                const float* __restrict__ g1b, const float* __restrict__ g2b,
                                                int* __restrict__ cursor,
                                                int* __restrict__ esrc, float* __restrict__ a1, float* __restrict__ a2) {
    int e = blockIdx.x*256 + threadIdx.x;
    if (e >= N_EDGESC) return;
    const int tt = etype[e], dd = edist[e];
    const float z1 = tbl[tt]       + tbl[50 + dd]  + g1b[0];
    const float z2 = tbl[178 + tt] + tbl[228 + dd] + g2b[0];
    const int pos = atomicAdd(&cursor[dst[e]], 1);
    esrc[pos] = src[e];
    a1[pos] = 1.f / (1.f + expf(-z1));
    a2[pos] = 1.f / (1.f + expf(-z2));
}

// ---------------------------------------------------------------------------
// K2: bf16 MFMA GEMM1: C[50000 x 512] = xb @ [W1_msg | W1_root]
// DOUBLE-BUFFERED 64KB LDS, one barrier per K-step. Staging in NAMED uint4
// registers (macros, no lambdas/arrays -> no scratch; r6/r7's 300MB
// WRITE_SIZE anomaly). msg half -> xtb (bf16), root half -> h (f32, +b1).
// ---------------------------------------------------------------------------
#define G1_BK 64
#define G1_NT (IN_DIM / G1_BK)   // 12

#define G1_LOAD(kb) do {                                                        \
    if (avalid) {                                                               \
        const uint4* pa_ = (const uint4*)(ap + (kb));                           \
        av0 = pa_[0]; av1 = pa_[1]; av2 = pa_[2]; av3 = pa_[3];                 \
    } else {                                                                    \
        av0 = make_uint4(0u,0u,0u,0u); av1 = av0; av2 = av0; av3 = av0;         \
    }                                                                           \
    const uint4* pb_ = (const uint4*)(bp + (kb));                               \
    bv0 = pb_[0]; bv1 = pb_[1]; bv2 = pb_[2]; bv3 = pb_[3];                     \
} while (0)

#define G1_STORE(wA, wB) do {                                                   \
    *(uint4*)((wA) + swz2(sr, wb))      = av0;                                  \
    *(uint4*)((wA) + swz2(sr, wb+16))   = av1;                                  \
    *(uint4*)((wA) + swz2(sr, wb+32))   = av2;                                  \
    *(uint4*)((wA) + swz2(sr, wb+48))   = av3;                                  \
    *(uint4*)((wB) + swz2(sr, wb))      = bv0;                                  \
    *(uint4*)((wB) + swz2(sr, wb+16))   = bv1;                                  \
    *(uint4*)((wB) + swz2(sr, wb+32))   = bv2;                                  \
    *(uint4*)((wB) + swz2(sr, wb+48))   = bv3;                                  \
} while (0)

__global__ __launch_bounds__(256) void gemm1_mfma(const ushort* __restrict__ xb,
                                                  const ushort* __restrict__ BTh,
                                                  const float* __restrict__ b1,
                                                  ushort* __restrict__ xtb,
                                                  float* __restrict__ h) {
    __shared__ __align__(16) ushort A0[128*G1_BK];   // 16KB each; 64KB total
    __shared__ __align__(16) ushort B0[128*G1_BK];
    __shared__ __align__(16) ushort A1[128*G1_BK];
    __shared__ __align__(16) ushort B1[128*G1_BK];

    const int t    = threadIdx.x;
    const int wave = t >> 6, lane = t & 63;
    const int wm   = wave >> 1, wn = wave & 1;
    const int nb   = blockIdx.x;         // 0..3 column block (x-fastest)
    const int m0   = blockIdx.y * 128;
    const int n0   = nb * 128;

    // staging maps: 2 threads/row, 32 bf16 (64B) each
    const int sr = t >> 1;
    const int sk = (t & 1) * 32;
    const int arow   = m0 + sr;
    const bool avalid = arow < N_NODES;
    const ushort* ap = xb  + (size_t)(avalid ? arow : 0) * IN_DIM + sk;
    const ushort* bp = BTh + (size_t)(n0 + sr) * IN_DIM + sk;

    const int fr = lane & 15;
    const int kg = lane >> 4;

    f32x4 acc[4][4];
    #pragma unroll
    for (int i=0;i<4;i++)
        #pragma unroll
        for (int j=0;j<4;j++) acc[i][j] = (f32x4){0.f,0.f,0.f,0.f};

    uint4 av0, av1, av2, av3, bv0, bv1, bv2, bv3;

    char* const cA0 = (char*)A0;
    char* const cB0 = (char*)B0;
    char* const cA1 = (char*)A1;
    char* const cB1 = (char*)B1;
    const int wb = sr*128 + sk*2;        // base byte of this thread's 64B slot

    // prologue: tile 0 -> buf0
    G1_LOAD(0);
    G1_STORE(cA0, cB0);
    __syncthreads();

    int cur = 0;
    for (int it = 0; it < G1_NT; ++it) {
        char* const rA = cur ? cA1 : cA0;
        char* const rB = cur ? cB1 : cB0;
        char* const wA = cur ? cA0 : cA1;
        char* const wB = cur ? cB0 : cB1;

        if (it + 1 < G1_NT) G1_LOAD((it+1)*G1_BK);   // issue early; hides under MFMA

        #pragma unroll
        for (int kk=0; kk<2; kk++) {
            bf16x8 af[4], bfv[4];
            #pragma unroll
            for (int i=0;i<4;i++) {
                const int r = wm*64 + i*16 + fr;
                af[i] = *(const bf16x8*)(rA + swz2(r, r*128 + kk*64 + kg*16));
            }
            #pragma unroll
            for (int j=0;j<4;j++) {
                const int c = wn*64 + j*16 + fr;
                bfv[j] = *(const bf16x8*)(rB + swz2(c, c*128 + kk*64 + kg*16));
            }
            #pragma unroll
            for (int i=0;i<4;i++)
                #pragma unroll
                for (int j=0;j<4;j++)
                    acc[i][j] = __builtin_amdgcn_mfma_f32_16x16x32_bf16(af[i], bfv[j], acc[i][j], 0, 0, 0);
        }

        if (it + 1 < G1_NT) G1_STORE(wA, wB);        // waits vmcnt, writes idle buf
        __syncthreads();
        cur ^= 1;
    }

    // epilogue: C/D map col=lane&15, row=(lane>>4)*4+reg  [m89/m91]
    const bool is_root = (nb >= 2);
    if (is_root) {
        const int cb = n0 - 256;
        #pragma unroll
        for (int j=0;j<4;j++) {
            const int col  = cb + wn*64 + j*16 + fr;
            const float bias = b1[col];
            #pragma unroll
            for (int i=0;i<4;i++) {
                const int rbase = m0 + wm*64 + i*16 + kg*4;
                #pragma unroll
                for (int r=0;r<4;r++) {
                    const int row = rbase + r;
                    if (row < N_NODES) h[(size_t)row*HID + col] = acc[i][j][r] + bias;
                }
            }
        }
    } else {
        #pragma unroll
        for (int j=0;j<4;j++) {
            const int col = n0 + wn*64 + j*16 + fr;
            #pragma unroll
            for (int i=0;i<4;i++) {
                const int rbase = m0 + wm*64 + i*16 + kg*4;
                #pragma unroll
                for (int r=0;r<4;r++) {
                    const int row = rbase + r;
                    if (row < N_NODES) xtb[(size_t)row*HID + col] = f2bf(acc[i][j][r]);
                }
            }
        }
    }
}

// ---------------------------------------------------------------------------
// K3: gather1 — one wave per dst node, EIGHT edges in flight; NAMED uint4
// loads (no arrays -> no scratch). Fold via shfl_xor 8/16/32; fused epilogue.
// ---------------------------------------------------------------------------
__global__ __launch_bounds__(256) void gather1(const int* __restrict__ rowptr,
                                               const int* __restrict__ esrc, const float* __restrict__ a1,
                                               const ushort* __restrict__ xtb,
                                               const float* __restrict__ h,
                                               const float* __restrict__ drop1,
                                               ushort* __restrict__ hb) {
    const int node = blockIdx.x*4 + (threadIdx.x >> 6);
    const int lane = threadIdx.x & 63;
    if (node >= N_NODES) return;
    const int g = lane >> 3, li = lane & 7;
    const int colbase = li*32;           // 32 bf16 = 64B per lane
    const int beg = rowptr[node], end = rowptr[node+1];

    float acc[32];
    #pragma unroll
    for (int q=0;q<32;q++) acc[q] = 0.f;

    for (int j = beg; j < end; j += 8) {
        const int jj = j + g;
        int s = 0; float a = 0.f;
        if (jj < end) { s = esrc[jj]; a = a1[jj]; }
        const uint4* sp = (const uint4*)(xtb + (size_t)s*HID + colbase);
        const uint4 va = sp[0];
        const uint4 vb = sp[1];
        const uint4 vc = sp[2];
        const uint4 vd = sp[3];
        const uint w0=va.x, w1=va.y, w2=va.z, w3=va.w;
        const uint w4=vb.x, w5=vb.y, w6=vb.z, w7=vb.w;
        const uint w8=vc.x, w9=vc.y, w10=vc.z, w11=vc.w;
        const uint w12=vd.x, w13=vd.y, w14=vd.z, w15=vd.w;
        #define G1ACC(q, w) \
            acc[2*(q)]   = fmaf(a, bf2f((ushort)((w) & 0xffffu)), acc[2*(q)]); \
            acc[2*(q)+1] = fmaf(a, bf2f((ushort)((w) >> 16)),     acc[2*(q)+1]);
        G1ACC(0,w0)  G1ACC(1,w1)  G1ACC(2,w2)  G1ACC(3,w3)
        G1ACC(4,w4)  G1ACC(5,w5)  G1ACC(6,w6)  G1ACC(7,w7)
        G1ACC(8,w8)  G1ACC(9,w9)  G1ACC(10,w10) G1ACC(11,w11)
        G1ACC(12,w12) G1ACC(13,w13) G1ACC(14,w14) G1ACC(15,w15)
        #undef G1ACC
    }
    #pragma unroll
    for (int q=0;q<32;q++) {
        acc[q] += __shfl_xor(acc[q], 8, 64);
        acc[q] += __shfl_xor(acc[q], 16, 64);
        acc[q] += __shfl_xor(acc[q], 32, 64);
    }

    if (g == 0) {
        const float* hp = h + (size_t)node*HID + colbase;
        const float* dp = drop1 + (size_t)node*HID + colbase;
        uint o[16];
        #pragma unroll
        for (int q=0;q<16;q++) {
            const float2 hv = ((const float2*)hp)[q];
            const float2 dv = ((const float2*)dp)[q];
            float m0 = (dv.x >= P_DROP) ? INV_KEEP : 0.f;
            float m1 = (dv.y >= P_DROP) ? INV_KEEP : 0.f;
            float f0 = fmaxf((hv.x + acc[2*q])   * m0, 0.f);
            float f1 = fmaxf((hv.y + acc[2*q+1]) * m1, 0.f);
            o[q] = pack_bf2(f0, f1);
        }
        ushort* op = hb + (size_t)node*HID + colbase;
        *(uint4*)(op)      = make_uint4(o[0],o[1],o[2],o[3]);
        *(uint4*)(op + 8)  = make_uint4(o[4],o[5],o[6],o[7]);
        *(uint4*)(op + 16) = make_uint4(o[8],o[9],o[10],o[11]);
        *(uint4*)(op + 24) = make_uint4(o[12],o[13],o[14],o[15]);
    }
}

// ---------------------------------------------------------------------------
// K4: gemm2 MFMA: [128 rows x 32 cols] = hb[128 x 256] @ WPT^T.
// ---------------------------------------------------------------------------
__global__ __launch_bounds__(256) void gemm2_mfma(const ushort* __restrict__ hb,
                                                  const ushort* __restrict__ WPT,
                                                  const float* __restrict__ b2,
                                                  float* __restrict__ ht2, float* __restrict__ root2) {
    __shared__ __align__(16) ushort As[128*256];   // 64KB, 512B rows, swizzled
    __shared__ __align__(16) ushort Bs[32*256];    // 16KB

    const int t = threadIdx.x;
    const int m0 = blockIdx.x * 128;
    char* const cAs = (char*)As;
    char* const cBs = (char*)Bs;

    #pragma unroll
    for (int i = 0; i < 4; ++i) {                  // stage B: 8192 elems / 8 per uint4
        const int idx = (i*256 + t) * 8;
        const int row = idx >> 8, col = idx & 255;
        const uint4 v = *(const uint4*)(WPT + row*256 + col);
        *(uint4*)(cBs + swz2(row, row*512 + col*2)) = v;
    }
    #pragma unroll
    for (int i = 0; i < 16; ++i) {                 // stage A: 32768 elems / 8 per uint4
        const int idx = (i*256 + t) * 8;
        const int row = idx >> 8, col = idx & 255;
        const int gr = m0 + row;
        uint4 v = make_uint4(0u,0u,0u,0u);
        if (gr < N_NODES) v = *(const uint4*)(hb + (size_t)gr*HID + col);
        *(uint4*)(cAs + swz2(row, row*512 + col*2)) = v;
    }
    __syncthreads();

    const int w = t >> 6, lane = t & 63;
    const int fr = lane & 15, kg = lane >> 4;

    f32x4 acc[2][2];
    #pragma unroll
    for (int i=0;i<2;i++)
        #pragma unroll
        for (int j=0;j<2;j++) acc[i][j] = (f32x4){0.f,0.f,0.f,0.f};

    #pragma unroll
    for (int ks = 0; ks < 8; ++ks) {
        bf16x8 af[2], bfv[2];
        #pragma unroll
        for (int i=0;i<2;i++) {
            const int r = w*32 + i*16 + fr;
            af[i] = *(const bf16x8*)(cAs + swz2(r, r*512 + ks*64 + kg*16));
        }
        #pragma unroll
        for (int j=0;j<2;j++) {
            const int c = j*16 + fr;
            bfv[j] = *(const bf16x8*)(cBs + swz2(c, c*512 + ks*64 + kg*16));
        }
        #pragma unroll
        for (int i=0;i<2;i++)
            #pragma unroll
            for (int j=0;j<2;j++)
                acc[i][j] = __builtin_amdgcn_mfma_f32_16x16x32_bf16(af[i], bfv[j], acc[i][j], 0, 0, 0);
    }

    if (fr < OUT_DIM) {
        const float bias = b2[fr];
        #pragma unroll
        for (int i=0;i<2;i++) {
            const int rbase = m0 + w*32 + i*16 + kg*4;
            #pragma unroll
            for (int r=0;r<4;r++) {
                const int row = rbase + r;
                if (row < N_NODES) {
                    ht2  [(size_t)row*OUT_DIM + fr] = acc[i][0][r];
                    root2[(size_t)row*OUT_DIM + fr] = acc[i][1][r] + bias;
                }
            }
        }
    }
}

// ---------------------------------------------------------------------------
// K5: gather2 — one thread per node, 9-float accumulator; fused relu-dropout.
// ---------------------------------------------------------------------------
__global__ __launch_bounds__(256) void gather2(const int* __restrict__ rowptr,
                                               const int* __restrict__ esrc, const float* __restrict__ a2,
                                               const float* __restrict__ ht2,
                                               const float* __restrict__ root2,
                                               const float* __restrict__ drop2,
                                               float* __restrict__ outp) {
    const int n = blockIdx.x*256 + threadIdx.x;
    if (n >= N_NODES) return;
    float acc[OUT_DIM];
    #pragma unroll
    for (int k=0;k<OUT_DIM;k++) acc[k] = root2[(size_t)n*OUT_DIM + k];
    const int beg = rowptr[n], end = rowptr[n+1];
    for (int j = beg; j < end; ++j) {
        const int s = esrc[j];
        const float a = a2[j];
        const float* sp = ht2 + (size_t)s*OUT_DIM;
        #pragma unroll
        for (int k=0;k<OUT_DIM;k++) acc[k] = fmaf(a, sp[k], acc[k]);
    }
    #pragma unroll
    for (int k=0;k<OUT_DIM;k++) {
        const float m = (drop2[(size_t)n*OUT_DIM + k] >= P_DROP) ? INV_KEEP : 0.f;
        const float v = acc[k]*m;
        outp[(size_t)n*OUT_DIM + k] = v > 0.f ? v : 0.f;
    }
}

// ---------------------------------------------------------------------------
extern "C" void kernel_launch(void* const* d_in, const int* in_sizes, int n_in,
                              void* d_out, int out_size, void* d_ws, size_t ws_size,
                              hipStream_t stream) {
    const float* x      = (const float*)d_in[0];
    const int*   eidx   = (const int*)d_in[1];
    const int*   etype  = (const int*)d_in[2];
    const int*   edist  = (const int*)d_in[3];
    const float* drop1  = (const float*)d_in[4];
    const float* drop2  = (const float*)d_in[5];
    const float* W1m    = (const float*)d_in[6];
    const float* W1r    = (const float*)d_in[7];
    const float* b1     = (const float*)d_in[8];
    const float* te1    = (const float*)d_in[9];
    const float* de1    = (const float*)d_in[10];
    const float* g1w    = (const float*)d_in[11];
    const float* g1b    = (const float*)d_in[12];
    const float* W2m    = (const float*)d_in[13];
    const float* W2r    = (const float*)d_in[14];
    const float* b2     = (const float*)d_in[15];
    const float* te2    = (const float*)d_in[16];
    const float* de2    = (const float*)d_in[17];
    const float* g2w    = (const float*)d_in[18];
    const float* g2b    = (const float*)d_in[19];
    float* out = (float*)d_out;

    const int* src = eidx;
    const int* dst = eidx + N_EDGESC;

    // workspace layout (~168MB); hb aliases xb (xb dead after gemm1)
    float* ws    = (float*)d_ws;
    float* h     = ws;                                   // 12,800,000 f
    float* ht2   = h     + (size_t)N_NODES*HID;          // 450,000 f
    float* root2 = ht2   + (size_t)N_NODES*OUT_DIM;      // 450,000 f
    float* tbl   = root2 + (size_t)N_NODES*OUT_DIM;      // 384 f
    float* a1    = tbl   + 384;                          // 800,000 f
    float* a2    = a1    + N_EDGESC;                     // 800,000 f
    int*   esrc  = (int*)(a2 + N_EDGESC);                // 800,000 i
    int*   deg   = esrc  + N_EDGESC;                     // 50,000 i
    int*   rowptr= deg   + N_NODES;                      // -> pad 50,004
    int*   cursor= rowptr+ 50004;                        // -> pad 50,004
    int*   bsum  = cursor+ 50004;                        // pad 256
    int*   boff  = bsum  + 256;                          // pad 256
    ushort* xtb  = (ushort*)(boff + 256);                // 12,800,000 u16
    ushort* xb   = xtb + (size_t)N_NODES*HID;            // 38,400,000 u16
    ushort* hb   = xb;                                   // alias: 12,800,000 u16
    ushort* BTh  = xb  + (size_t)N_NODES*IN_DIM;         // 393,216 u16
    ushort* WPT  = BTh + (size_t)512*IN_DIM;             // 8,192 u16

    xprep<<<2048, 256, 0, stream>>>(x, xb);
    gate_tables<<<1, 512, 0, stream>>>(te1, de1, g1w, te2, de2, g2w, tbl);
    bt_prep<<<(512*IN_DIM+255)/256, 256, 0, stream>>>(W1m, W1r, BTh);
    w2_pack<<<32, 256, 0, stream>>>(W2m, W2r, WPT);
    zero_deg<<<(N_NODES+255)/256, 256, 0, stream>>>(deg);
    hist<<<(N_EDGESC+255)/256, 256, 0, stream>>>(dst, deg);
    scan_p1<<<196, 256, 0, stream>>>(deg, bsum);
    scan_p2<<<1, 256, 0, stream>>>(bsum, boff);
    scan_p3<<<196, 256, 0, stream>>>(deg, boff, rowptr, cursor);
    fill_csr<<<(N_EDGESC+255)/256, 256, 0, stream>>>(src, dst, etype, edist, tbl, g1b, g2b,
                                                     cursor, esrc, a1, a2);
    gemm1_mfma<<<dim3(4, (N_NODES+127)/128), 256, 0, stream>>>(xb, BTh, b1, xtb, h);
    gather1<<<(N_NODES+3)/4, 256, 0, stream>>>(rowptr, esrc, a1, xtb, h, drop1, hb);
    gemm2_mfma<<<(N_NODES+127)/128, 256, 0, stream>>>(hb, WPT, b2, ht2, root2);
    gather2<<<(N_NODES+255)/256, 256, 0, stream>>>(rowptr, esrc, a2, ht2, root2, drop2, out);
}